// Round 6
// baseline (43253.012 us; speedup 1.0000x reference)
//
#include <hip/hip_runtime.h>
#include <math.h>

#define BDIM   262144
#define IN_DIM 54
#define HID    256
#define EXPD   512
#define LAT    32
#define NBLK   4
#define NCODES 512
#define EPS    1e-5

#define ROWS   32      // rows per block (both kernels)
#define R0S    36      // r0 column stride in floats (32 rows + 4 pad; float4-aligned)
#define BTE    1024    // encoder threads
#define BTD    512     // decoder threads

// d_out layout (floats): x_recon | z_q_st | indices | commit_loss
#define O_ZQ   14155776
#define O_IDX  22544384
#define O_LOSS 22806528

// encoder smem (bytes): r0 [0,36864) | r1 [36864,102400) 64KB slabs | zbuf [102400,111104)
//   ccs (512 f64) overlays r1 after Wl is dead; 1 block/CU (LDS-bound)
//   __launch_bounds__(1024,1): 1 block x 16 waves = 4 waves/EU -> 128-VGPR cap (no spill, demand ~92)
// decoder smem (bytes): r0 [0,36864) | r1 [36864,69632) 32KB slabs; (512,2) -> 128-VGPR cap

__device__ __forceinline__ double gelu_d(double x) {
    return 0.5 * x * (1.0 + erf(x * 0.70710678118654752440));
}
__device__ __forceinline__ float gelu_f(float x) {
    return 0.5f * x * (1.0f + erff(x * 0.70710678f));
}

// ===========================================================================
// ENCODER side (f64 acc, f32 LDS storage, BTE=1024 threads, ROWS=32)
// ===========================================================================

// LayerNorm: acc[2][4] (row rt*2+i, col ct*4+j), rt=tid>>6 in 0..15 (1 wave
// owns 2 rows), ct=tid&63. Normalized f32 -> r0 transposed [c][R0S].
__device__ __forceinline__ void ln_e(double acc[2][4], float* r0,
    const float* __restrict__ g, const float* __restrict__ bta,
    const float* __restrict__ b2, int rt, int ct)
{
    double s[2], sq[2];
    #pragma unroll
    for (int i = 0; i < 2; i++) {
        s[i]  = acc[i][0] + acc[i][1] + acc[i][2] + acc[i][3];
        sq[i] = acc[i][0]*acc[i][0] + acc[i][1]*acc[i][1]
              + acc[i][2]*acc[i][2] + acc[i][3]*acc[i][3];
    }
    #pragma unroll
    for (int m = 1; m < 64; m <<= 1) {
        #pragma unroll
        for (int i = 0; i < 2; i++) {
            s[i]  += __shfl_xor(s[i],  m);
            sq[i] += __shfl_xor(sq[i], m);
        }
    }
    float4 gv = *(const float4*)(g + ct*4);
    float4 bv = *(const float4*)(bta + ct*4);
    float gj[4] = {gv.x, gv.y, gv.z, gv.w};
    float bj[4] = {bv.x, bv.y, bv.z, bv.w};
    double mu[2], rs[2];
    #pragma unroll
    for (int i = 0; i < 2; i++) {
        mu[i] = s[i] * (1.0 / HID);
        double var = sq[i] * (1.0 / HID) - mu[i] * mu[i];
        rs[i] = 1.0 / sqrt(var + EPS);
    }
    #pragma unroll
    for (int j = 0; j < 4; j++) {
        float2 o;
        o.x = (float)((acc[0][j] - mu[0]) * rs[0] * (double)gj[j] + (double)bj[j]);
        o.y = (float)((acc[1][j] - mu[1]) * rs[1] * (double)gj[j] + (double)bj[j]);
        *(float2*)(r0 + (ct*4 + j)*R0S + rt*2) = o;
    }
    if (b2) {
        float4 b2v = *(const float4*)(b2 + ct*4);
        float bb[4] = {b2v.x, b2v.y, b2v.z, b2v.w};
        #pragma unroll
        for (int i = 0; i < 2; i++)
            #pragma unroll
            for (int j = 0; j < 4; j++)
                acc[i][j] += (double)bb[j];
    }
}

// GEMM1: y[32 x 512] = aT[256][R0S] @ W1[256][512], k-slabs of 32 rows (64KB).
// Thread tile 4x4: rows rt1*4 (rt1=tid>>7 in 0..7), cols ct1*4 (ct1=tid&127).
__device__ __forceinline__ void gemm1_e(double yacc[4][4], const float* __restrict__ W1,
                                        const float* r0, float* r1, int rt1, int ct1, int tid)
{
    #pragma unroll
    for (int i = 0; i < 4; i++)
        #pragma unroll
        for (int j = 0; j < 4; j++) yacc[i][j] = 0;
    float4 R[4];
    #pragma unroll
    for (int u = 0; u < 4; u++) R[u] = *(const float4*)(W1 + (tid + BTE*u)*4);
    for (int k0 = 0; k0 < HID; k0 += 32) {
        #pragma unroll
        for (int u = 0; u < 4; u++) *(float4*)(r1 + (tid + BTE*u)*4) = R[u];
        __syncthreads();
        if (k0 + 32 < HID) {
            const float* src = W1 + (long)(k0 + 32) * EXPD;
            #pragma unroll
            for (int u = 0; u < 4; u++) R[u] = *(const float4*)(src + (tid + BTE*u)*4);
        }
        #pragma unroll 2
        for (int k = 0; k < 32; k++) {
            float4 av = *(const float4*)(r0 + (k0 + k)*R0S + rt1*4);    // broadcast
            float4 wv = *(const float4*)(r1 + k*EXPD + ct1*4);          // contiguous
            double a[4] = {(double)av.x, (double)av.y, (double)av.z, (double)av.w};
            double w[4] = {(double)wv.x, (double)wv.y, (double)wv.z, (double)wv.w};
            #pragma unroll
            for (int i = 0; i < 4; i++)
                #pragma unroll
                for (int j = 0; j < 4; j++)
                    yacc[i][j] += a[i] * w[j];
        }
        __syncthreads();
    }
}

// GEMM2-style accumulate: acc[2][4] += aT[E][R0S] @ W[E][256], e-slabs of 64
// rows (64KB). Thread tile 2x4: rows rt*2 (rt=tid>>6), cols ct*4 (ct=tid&63).
__device__ __forceinline__ void gemm2_e(double acc[2][4], const float* __restrict__ W, int E,
                                        const float* r0, float* r1, int rt, int ct, int tid)
{
    float4 R[4];
    {
        int n0 = (E < 64 ? E : 64) * 64;           // float4s in first slab
        #pragma unroll
        for (int u = 0; u < 4; u++) {
            int idx = tid + BTE*u;
            if (idx < n0) R[u] = *(const float4*)(W + idx*4);
        }
    }
    for (int e0 = 0; e0 < E; e0 += 64) {
        int n = E - e0; if (n > 64) n = 64;
        #pragma unroll
        for (int u = 0; u < 4; u++) {
            int idx = tid + BTE*u;
            if (idx < n*64) *(float4*)(r1 + idx*4) = R[u];
        }
        __syncthreads();
        if (e0 + 64 < E) {
            int n2 = E - e0 - 64; if (n2 > 64) n2 = 64;
            const float* src = W + (long)(e0 + 64) * HID;
            #pragma unroll
            for (int u = 0; u < 4; u++) {
                int idx = tid + BTE*u;
                if (idx < n2*64) R[u] = *(const float4*)(src + idx*4);
            }
        }
        #pragma unroll 2
        for (int e = 0; e < n; e++) {
            float2 av = *(const float2*)(r0 + (e0 + e)*R0S + rt*2);     // broadcast
            float4 wv = *(const float4*)(r1 + e*HID + ct*4);            // contiguous
            double a[2] = {(double)av.x, (double)av.y};
            double w[4] = {(double)wv.x, (double)wv.y, (double)wv.z, (double)wv.w};
            #pragma unroll
            for (int i = 0; i < 2; i++)
                #pragma unroll
                for (int j = 0; j < 4; j++)
                    acc[i][j] += a[i] * w[j];
        }
        __syncthreads();
    }
}

__device__ __forceinline__ void ffn_layer_e(double acc[2][4], float* r0, float* r1,
    const float* lng, const float* lnb,
    const float* W1, const float* b1, const float* W2, const float* b2,
    int rt, int ct, int rt1, int ct1, int tid)
{
    ln_e(acc, r0, lng, lnb, b2, rt, ct);
    double yacc[4][4];
    gemm1_e(yacc, W1, r0, r1, rt1, ct1, tid);   // ends with barrier; r0 (A_ln) now dead
    const int h1 = ct1 >> 6;                    // which col-half this thread's yacc is in
    #pragma unroll
    for (int h = 0; h < 2; h++) {
        if (h1 == h) {
            float4 b1v = *(const float4*)(b1 + ct1*4);
            double bb[4] = {(double)b1v.x, (double)b1v.y, (double)b1v.z, (double)b1v.w};
            #pragma unroll
            for (int j = 0; j < 4; j++) {
                float4 o;
                o.x = (float)gelu_d(yacc[0][j] + bb[j]);
                o.y = (float)gelu_d(yacc[1][j] + bb[j]);
                o.z = (float)gelu_d(yacc[2][j] + bb[j]);
                o.w = (float)gelu_d(yacc[3][j] + bb[j]);
                *(float4*)(r0 + ((ct1 & 63)*4 + j)*R0S + rt1*4) = o;
            }
        }
        // barrier inside gemm2_e (after slab store) orders gelu writes vs reads
        gemm2_e(acc, W2 + (long)h*256*HID, 256, r0, r1, rt, ct, tid);
    }
}

__global__ __launch_bounds__(BTE, 1)
void k_encoder(const float* __restrict__ x,
               const float* __restrict__ epw, const float* __restrict__ epb,
               const float* __restrict__ lng, const float* __restrict__ lnb,
               const float* __restrict__ W1, const float* __restrict__ b1,
               const float* __restrict__ W2, const float* __restrict__ b2,
               const float* __restrict__ ng, const float* __restrict__ nb,
               const float* __restrict__ Wl, const float* __restrict__ bl,
               const float* __restrict__ cb, float* __restrict__ dout)
{
    __shared__ __align__(16) char smem[111104];
    float*  r0   = (float*)smem;
    float*  r1   = (float*)(smem + 36864);
    double* zbuf = (double*)(smem + 102400);
    double* ccs  = (double*)(smem + 36864);     // overlays r1 (valid after Wl use)
    const int tid = threadIdx.x;
    const int rt = tid >> 6, ct = tid & 63;          // acc map: rows rt*2+i
    const int rt1 = tid >> 7, ct1 = tid & 127;       // gemm1 map: 4x4 tiles
    const long row0 = (long)blockIdx.x * ROWS;

    // stage xT [54][R0S]
    #pragma unroll
    for (int u = 0; u < 2; u++) {
        int idx = tid + BTE*u;
        if (idx < ROWS * IN_DIM) {
            int r = idx / IN_DIM, c = idx % IN_DIM;
            r0[c*R0S + r] = x[row0*IN_DIM + idx];
        }
    }
    double acc[2][4];
    {
        float4 bv = *(const float4*)(epb + ct*4);
        float bb[4] = {bv.x, bv.y, bv.z, bv.w};
        #pragma unroll
        for (int i = 0; i < 2; i++)
            #pragma unroll
            for (int j = 0; j < 4; j++) acc[i][j] = (double)bb[j];
    }
    gemm2_e(acc, epw, IN_DIM, r0, r1, rt, ct, tid);

    for (int l = 0; l < NBLK; l++)
        ffn_layer_e(acc, r0, r1, lng + l*HID, lnb + l*HID,
                    W1 + (long)l*HID*EXPD, b1 + l*EXPD,
                    W2 + (long)l*EXPD*HID, b2 + l*HID, rt, ct, rt1, ct1, tid);

    // final encoder LN
    ln_e(acc, r0, ng, nb, nullptr, rt, ct);
    // stage Wl [256][32] into r1 (32KB of it)
    #pragma unroll
    for (int u = 0; u < 2; u++)
        *(float4*)(r1 + (tid + BTE*u)*4) = *(const float4*)(Wl + (tid + BTE*u)*4);
    __syncthreads();                               // r0 (LN out) + r1 (Wl) ready

    // latent projection: r in 0..31, q in 0..31 (one latent col each)
    const int r = tid >> 5, q = tid & 31;
    {
        double z = (double)bl[q];
        #pragma unroll 4
        for (int k = 0; k < HID; k++) {
            double a = (double)r0[k*R0S + r];            // broadcast
            z += a * (double)r1[k*LAT + q];
        }
        zbuf[r*34 + q] = z;
    }
    __syncthreads();                                     // Wl dead; zbuf ready

    // codebook norms into ccs (overlaying r1): one code per thread (512 of 1024)
    if (tid < NCODES) {
        const float* cp = cb + (long)tid * LAT;
        double sc = 0;
        #pragma unroll
        for (int j = 0; j < LAT; j += 4) {
            float4 v = *(const float4*)(cp + j);
            sc += (double)v.x*(double)v.x + (double)v.y*(double)v.y
                + (double)v.z*(double)v.z + (double)v.w*(double)v.w;
        }
        ccs[tid] = sc;
    }
    __syncthreads();

    // VQ: thread (r,q) scans codes q*16..q*16+15
    double bd; int bi;
    {
        double zr[32];
        #pragma unroll
        for (int j = 0; j < LAT; j++) zr[j] = zbuf[r*34 + j];
        double zz = 0;
        #pragma unroll
        for (int j = 0; j < LAT; j++) zz += zr[j]*zr[j];
        bd = 1e300; bi = 0;
        for (int c0 = 0; c0 < 16; c0++) {
            int code = q*16 + c0;
            const float* cp = cb + (long)code * LAT;
            double dot = 0;
            #pragma unroll
            for (int j = 0; j < LAT; j += 4) {
                float4 v = *(const float4*)(cp + j);
                dot += zr[j]*(double)v.x + zr[j+1]*(double)v.y
                     + zr[j+2]*(double)v.z + zr[j+3]*(double)v.w;
            }
            double d2 = (zz - 2.0*dot) + ccs[code];
            if (d2 < bd) { bd = d2; bi = code; }         // strict <: first-min
        }
        #pragma unroll
        for (int m = 1; m < 32; m <<= 1) {
            double ob = __shfl_xor(bd, m);
            int obi = __shfl_xor(bi, m);
            if (ob < bd || (ob == bd && obi < bi)) { bd = ob; bi = obi; }
        }
        if (q == 0) {
            long grow = row0 + r;
            dout[O_IDX + grow] = (float)bi;
            const float* cq = cb + (long)bi * LAT;
            #pragma unroll
            for (int j = 0; j < LAT; j += 4)
                *(float4*)(dout + O_ZQ + grow*LAT + j) = *(const float4*)(cq + j);
        }
    }
    // commit loss: wave sums (2 rows/wave) -> block sum -> one atomic
    __syncthreads();                   // zbuf reads done; free for reuse
    double ws = bd;
    ws += __shfl_xor(ws, 32);          // sum the wave's 2 rows
    if ((tid & 63) == 0) zbuf[tid >> 6] = ws;
    __syncthreads();
    if (tid == 0) {
        double t = 0;
        #pragma unroll
        for (int w = 0; w < 16; w++) t += zbuf[w];
        atomicAdd(dout + O_LOSS, (float)t);
    }
}

// ===========================================================================
// DECODER side (f32, BTD=512 threads, ROWS=32) — round-3 proven structure
// ===========================================================================

__device__ __forceinline__ void ln_d(float acc[4][4], float* r0,
    const float* __restrict__ g, const float* __restrict__ bta,
    const float* __restrict__ b2, int rt, int ct)
{
    float s[4], sq[4];
    #pragma unroll
    for (int i = 0; i < 4; i++) {
        s[i]  = acc[i][0] + acc[i][1] + acc[i][2] + acc[i][3];
        sq[i] = acc[i][0]*acc[i][0] + acc[i][1]*acc[i][1]
              + acc[i][2]*acc[i][2] + acc[i][3]*acc[i][3];
    }
    #pragma unroll
    for (int m = 1; m < 64; m <<= 1) {
        #pragma unroll
        for (int i = 0; i < 4; i++) {
            s[i]  += __shfl_xor(s[i],  m);
            sq[i] += __shfl_xor(sq[i], m);
        }
    }
    float4 gv = *(const float4*)(g + ct*4);
    float4 bv = *(const float4*)(bta + ct*4);
    float gj[4] = {gv.x, gv.y, gv.z, gv.w};
    float bj[4] = {bv.x, bv.y, bv.z, bv.w};
    float mu[4], rs[4];
    #pragma unroll
    for (int i = 0; i < 4; i++) {
        mu[i] = s[i] * (1.0f / HID);
        float var = sq[i] * (1.0f / HID) - mu[i] * mu[i];
        rs[i] = 1.0f / sqrtf(var + (float)EPS);
    }
    #pragma unroll
    for (int j = 0; j < 4; j++) {
        float4 o;
        o.x = (acc[0][j] - mu[0]) * rs[0] * gj[j] + bj[j];
        o.y = (acc[1][j] - mu[1]) * rs[1] * gj[j] + bj[j];
        o.z = (acc[2][j] - mu[2]) * rs[2] * gj[j] + bj[j];
        o.w = (acc[3][j] - mu[3]) * rs[3] * gj[j] + bj[j];
        *(float4*)(r0 + (ct*4 + j)*R0S + rt*4) = o;
    }
    if (b2) {
        float4 b2v = *(const float4*)(b2 + ct*4);
        float bb[4] = {b2v.x, b2v.y, b2v.z, b2v.w};
        #pragma unroll
        for (int i = 0; i < 4; i++)
            #pragma unroll
            for (int j = 0; j < 4; j++)
                acc[i][j] += bb[j];
    }
}

// GEMM1: yacc[4][8] = rows rt*4..+3, cols ct*4..+3 and 256+ct*4..+3.
// k-slabs of 16 rows (32KB).
__device__ __forceinline__ void gemm1_d(float yacc[4][8], const float* __restrict__ W1,
                                        const float* r0, float* r1, int rt, int ct, int tid)
{
    #pragma unroll
    for (int i = 0; i < 4; i++)
        #pragma unroll
        for (int j = 0; j < 8; j++) yacc[i][j] = 0;
    float4 R[4];
    #pragma unroll
    for (int u = 0; u < 4; u++) R[u] = *(const float4*)(W1 + (tid + BTD*u)*4);
    for (int k0 = 0; k0 < HID; k0 += 16) {
        #pragma unroll
        for (int u = 0; u < 4; u++) *(float4*)(r1 + (tid + BTD*u)*4) = R[u];
        __syncthreads();
        if (k0 + 16 < HID) {
            const float* src = W1 + (long)(k0 + 16) * EXPD;
            #pragma unroll
            for (int u = 0; u < 4; u++) R[u] = *(const float4*)(src + (tid + BTD*u)*4);
        }
        #pragma unroll 2
        for (int k = 0; k < 16; k++) {
            float4 av = *(const float4*)(r0 + (k0 + k)*R0S + rt*4);     // broadcast
            float4 w0 = *(const float4*)(r1 + k*EXPD + ct*4);           // contiguous
            float4 w1 = *(const float4*)(r1 + k*EXPD + 256 + ct*4);
            float a[4]  = {av.x, av.y, av.z, av.w};
            float wv[8] = {w0.x, w0.y, w0.z, w0.w, w1.x, w1.y, w1.z, w1.w};
            #pragma unroll
            for (int i = 0; i < 4; i++)
                #pragma unroll
                for (int j = 0; j < 8; j++)
                    yacc[i][j] += a[i] * wv[j];
        }
        __syncthreads();
    }
}

// acc[4][4] += aT[E][R0S] @ W[E][256], e-slabs of 32 rows (32KB).
__device__ __forceinline__ void gemm2_d(float acc[4][4], const float* __restrict__ W, int E,
                                        const float* r0, float* r1, int rt, int ct, int tid)
{
    float4 R[4];
    {
        int n0 = (E < 32 ? E : 32) * 64;
        #pragma unroll
        for (int u = 0; u < 4; u++) {
            int idx = tid + BTD*u;
            if (idx < n0) R[u] = *(const float4*)(W + idx*4);
        }
    }
    for (int e0 = 0; e0 < E; e0 += 32) {
        int n = E - e0; if (n > 32) n = 32;
        #pragma unroll
        for (int u = 0; u < 4; u++) {
            int idx = tid + BTD*u;
            if (idx < n*64) *(float4*)(r1 + idx*4) = R[u];
        }
        __syncthreads();
        if (e0 + 32 < E) {
            int n2 = E - e0 - 32; if (n2 > 32) n2 = 32;
            const float* src = W + (long)(e0 + 32) * HID;
            #pragma unroll
            for (int u = 0; u < 4; u++) {
                int idx = tid + BTD*u;
                if (idx < n2*64) R[u] = *(const float4*)(src + idx*4);
            }
        }
        #pragma unroll 2
        for (int e = 0; e < n; e++) {
            float4 av = *(const float4*)(r0 + (e0 + e)*R0S + rt*4);     // broadcast
            float4 wv = *(const float4*)(r1 + e*HID + ct*4);            // contiguous
            float a[4] = {av.x, av.y, av.z, av.w};
            float w[4] = {wv.x, wv.y, wv.z, wv.w};
            #pragma unroll
            for (int i = 0; i < 4; i++)
                #pragma unroll
                for (int j = 0; j < 4; j++)
                    acc[i][j] += a[i] * w[j];
        }
        __syncthreads();
    }
}

__device__ __forceinline__ void ffn_layer_d(float acc[4][4], float* r0, float* r1,
    const float* lng, const float* lnb,
    const float* W1, const float* b1, const float* W2, const float* b2,
    int rt, int ct, int tid)
{
    ln_d(acc, r0, lng, lnb, b2, rt, ct);
    float yacc[4][8];
    gemm1_d(yacc, W1, r0, r1, rt, ct, tid);   // ends with barrier
    #pragma unroll
    for (int h = 0; h < 2; h++) {
        float4 b1v = *(const float4*)(b1 + h*256 + ct*4);
        float bb[4] = {b1v.x, b1v.y, b1v.z, b1v.w};
        #pragma unroll
        for (int j = 0; j < 4; j++) {
            float4 o;
            o.x = gelu_f(yacc[0][h*4 + j] + bb[j]);
            o.y = gelu_f(yacc[1][h*4 + j] + bb[j]);
            o.z = gelu_f(yacc[2][h*4 + j] + bb[j]);
            o.w = gelu_f(yacc[3][h*4 + j] + bb[j]);
            *(float4*)(r0 + (ct*4 + j)*R0S + rt*4) = o;
        }
        gemm2_d(acc, W2 + (long)h*256*HID, 256, r0, r1, rt, ct, tid);
    }
}

__global__ __launch_bounds__(BTD, 2)
void k_decoder(float* __restrict__ dout,
               const float* __restrict__ Wl, const float* __restrict__ bl,
               const float* __restrict__ lng, const float* __restrict__ lnb,
               const float* __restrict__ W1, const float* __restrict__ b1,
               const float* __restrict__ W2, const float* __restrict__ b2,
               const float* __restrict__ ng, const float* __restrict__ nb,
               const float* __restrict__ Wp, const float* __restrict__ pb)
{
    __shared__ __align__(16) char smem[69632];
    float* r0 = (float*)smem;
    float* r1 = (float*)(smem + 36864);
    const int tid = threadIdx.x;
    const int rt = tid >> 6, ct = tid & 63;
    const long row0 = (long)blockIdx.x * ROWS;

    // stage zqT [32][R0S]
    #pragma unroll
    for (int u = 0; u < 2; u++) {
        int idx = tid + BTD*u;                 // < 1024
        int r = idx >> 5, c = idx & 31;
        r0[c*R0S + r] = dout[O_ZQ + row0*LAT + idx];
    }
    float acc[4][4];
    {
        float4 bv = *(const float4*)(bl + ct*4);
        float bb[4] = {bv.x, bv.y, bv.z, bv.w};
        #pragma unroll
        for (int i = 0; i < 4; i++)
            #pragma unroll
            for (int j = 0; j < 4; j++) acc[i][j] = bb[j];
    }
    gemm2_d(acc, Wl, LAT, r0, r1, rt, ct, tid);

    for (int l = 0; l < NBLK; l++)
        ffn_layer_d(acc, r0, r1, lng + l*HID, lnb + l*HID,
                    W1 + (long)l*HID*EXPD, b1 + l*EXPD,
                    W2 + (long)l*EXPD*HID, b2 + l*HID, rt, ct, tid);

    ln_d(acc, r0, ng, nb, nullptr, rt, ct);

    // output projection, (r,q) map: r in 0..31, q in 0..15, 4 cols each
    const int r = tid >> 4, q = tid & 15;
    float oacc[4];
    #pragma unroll
    for (int j = 0; j < 4; j++) {
        int c = q*4 + j;
        oacc[j] = (c < IN_DIM) ? pb[c] : 0.f;
    }
    for (int k0 = 0; k0 < HID; k0 += 128) {
        #pragma unroll
        for (int u = 0; u < 4; u++) {
            int idx = tid + BTD*u;
            if (idx < 1728)                   // 128*54/4 float4s
                ((float4*)r1)[idx] = ((const float4*)(Wp + (long)k0*IN_DIM))[idx];
        }
        __syncthreads();
        #pragma unroll 4
        for (int k = 0; k < 128; k++) {
            float a = r0[(k0 + k)*R0S + r];   // broadcast
            #pragma unroll
            for (int j = 0; j < 4; j++)
                oacc[j] += a * r1[k*IN_DIM + q*4 + j];   // may read pad garbage for c>=54
        }
        __syncthreads();
    }
    #pragma unroll
    for (int j = 0; j < 4; j++) {
        int c = q*4 + j;
        if (c < IN_DIM) dout[(row0 + r)*IN_DIM + c] = oacc[j];
    }
}

__global__ void k_zero(float* p) { *p = 0.0f; }
__global__ void k_final(float* p) { *p = *p * (1.0f / 8388608.0f); }  // / (B*LAT) = 2^-23, exact

// ---------------------------------------------------------------------------
extern "C" void kernel_launch(void* const* d_in, const int* in_sizes, int n_in,
                              void* d_out, int out_size, void* d_ws, size_t ws_size,
                              hipStream_t stream)
{
    (void)in_sizes; (void)n_in; (void)out_size; (void)d_ws; (void)ws_size;
    const float* x     = (const float*)d_in[0];
    const float* epw   = (const float*)d_in[1];
    const float* epb   = (const float*)d_in[2];
    const float* elng  = (const float*)d_in[3];
    const float* elnb  = (const float*)d_in[4];
    const float* ew1   = (const float*)d_in[5];
    const float* eb1   = (const float*)d_in[6];
    const float* ew2   = (const float*)d_in[7];
    const float* eb2   = (const float*)d_in[8];
    const float* eng   = (const float*)d_in[9];
    const float* enb   = (const float*)d_in[10];
    const float* elatw = (const float*)d_in[11];
    const float* elatb = (const float*)d_in[12];
    const float* cbk   = (const float*)d_in[13];
    const float* dlatw = (const float*)d_in[14];
    const float* dlatb = (const float*)d_in[15];
    const float* dlng  = (const float*)d_in[16];
    const float* dlnb  = (const float*)d_in[17];
    const float* dw1   = (const float*)d_in[18];
    const float* db1   = (const float*)d_in[19];
    const float* dw2   = (const float*)d_in[20];
    const float* db2   = (const float*)d_in[21];
    const float* dng   = (const float*)d_in[22];
    const float* dnb   = (const float*)d_in[23];
    const float* dpw   = (const float*)d_in[24];
    const float* dpb   = (const float*)d_in[25];
    float* out = (float*)d_out;

    k_zero<<<1, 1, 0, stream>>>(out + O_LOSS);
    k_encoder<<<BDIM / ROWS, dim3(BTE), 0, stream>>>(
        x, epw, epb, elng, elnb, ew1, eb1, ew2, eb2, eng, enb, elatw, elatb, cbk, out);
    k_decoder<<<BDIM / ROWS, dim3(BTD), 0, stream>>>(
        out, dlatw, dlatb, dlng, dlnb, dw1, db1, dw2, db2, dng, dnb, dpw, dpb);
    k_final<<<1, 1, 0, stream>>>(out + O_LOSS);
}

// Round 7
// 37002.200 us; speedup vs baseline: 1.1689x; 1.1689x over previous
//
#include <hip/hip_runtime.h>
#include <math.h>

#define BDIM   262144
#define IN_DIM 54
#define HID    256
#define EXPD   512
#define LAT    32
#define NBLK   4
#define NCODES 512
#define EPS    1e-5

#define BT     512     // threads per block
#define ROWS   32      // rows per block
#define R0S    36      // r0 column stride in floats (32 rows + 4 pad; float4-aligned)

// d_out layout (floats): x_recon | z_q_st | indices | commit_loss
#define O_ZQ   14155776
#define O_IDX  22544384
#define O_LOSS 22806528

// smem layout (bytes):
//   r0 [0,36864):        activations, transposed [c][R0S] f32 (rows 0..31 per col)
//   r1 [36864,69632):    weight slabs / Wl / dpw chunks (32KB)
//   enc: zbuf [69632,78336): 32*34 f64;  ccs overlays r1 after Wl is dead
//
// Register-cap ladder (measured this session): (512,4)->64 VGPR (massive f64
// spill, 35GB scratch); (512,2)->128 cap, 92 VGPR measured no-spill.
// Encoder: (512,2) -> demand ~130 just grazes the 128 cap (tiny spill), 2
// blocks/CU x 8 waves. Decoder: f32 spill at 32 waves/CU measured FASTER than
// no-spill at 16 waves -> keep (512,4).

template<typename T> __device__ __forceinline__ T gelu_T(T x);
template<> __device__ __forceinline__ double gelu_T<double>(double x) {
    return 0.5 * x * (1.0 + erf(x * 0.70710678118654752440));
}
template<> __device__ __forceinline__ float gelu_T<float>(float x) {
    return 0.5f * x * (1.0f + erff(x * 0.70710678f));
}
template<typename T> __device__ __forceinline__ T rsqrt_T(T x);
template<> __device__ __forceinline__ double rsqrt_T<double>(double x) { return 1.0 / sqrt(x); }
template<> __device__ __forceinline__ float  rsqrt_T<float>(float x)  { return 1.0f / sqrtf(x); }

// ---------------------------------------------------------------------------
// LayerNorm: acc[4][4] regs (row rt*4+i, col ct*4+j) -> normalized f32 into
// r0 transposed [c][R0S]. Wave-local shfl reduction (each wave owns 4 rows).
// Writes are float4 over the 4 rows (conflict-light vs scalar same-bank).
// If b2 != null, preload residual bias into acc for the FFN accumulate.
// ---------------------------------------------------------------------------
template<typename T>
__device__ __forceinline__ void ln_to_abuf(T acc[4][4], float* r0,
    const float* __restrict__ g, const float* __restrict__ bta,
    const float* __restrict__ b2, int rt, int ct)
{
    T s[4], sq[4];
    #pragma unroll
    for (int i = 0; i < 4; i++) {
        s[i]  = acc[i][0] + acc[i][1] + acc[i][2] + acc[i][3];
        sq[i] = acc[i][0]*acc[i][0] + acc[i][1]*acc[i][1]
              + acc[i][2]*acc[i][2] + acc[i][3]*acc[i][3];
    }
    #pragma unroll
    for (int m = 1; m < 64; m <<= 1) {
        #pragma unroll
        for (int i = 0; i < 4; i++) {
            s[i]  += __shfl_xor(s[i],  m);
            sq[i] += __shfl_xor(sq[i], m);
        }
    }
    float4 gv = *(const float4*)(g + ct*4);
    float4 bv = *(const float4*)(bta + ct*4);
    float gj[4] = {gv.x, gv.y, gv.z, gv.w};
    float bj[4] = {bv.x, bv.y, bv.z, bv.w};
    T mu[4], rs[4];
    #pragma unroll
    for (int i = 0; i < 4; i++) {
        mu[i] = s[i] * (T)(1.0 / HID);
        T var = sq[i] * (T)(1.0 / HID) - mu[i] * mu[i];
        rs[i] = rsqrt_T<T>(var + (T)EPS);
    }
    #pragma unroll
    for (int j = 0; j < 4; j++) {
        float4 o;
        o.x = (float)((acc[0][j] - mu[0]) * rs[0] * (T)gj[j] + (T)bj[j]);
        o.y = (float)((acc[1][j] - mu[1]) * rs[1] * (T)gj[j] + (T)bj[j]);
        o.z = (float)((acc[2][j] - mu[2]) * rs[2] * (T)gj[j] + (T)bj[j]);
        o.w = (float)((acc[3][j] - mu[3]) * rs[3] * (T)gj[j] + (T)bj[j]);
        *(float4*)(r0 + (ct*4 + j)*R0S + rt*4) = o;
    }
    if (b2) {
        float4 b2v = *(const float4*)(b2 + ct*4);
        float bb[4] = {b2v.x, b2v.y, b2v.z, b2v.w};
        #pragma unroll
        for (int i = 0; i < 4; i++)
            #pragma unroll
            for (int j = 0; j < 4; j++)
                acc[i][j] += (T)bb[j];
    }
}

// ---------------------------------------------------------------------------
// GEMM1: yacc[32 rows x 512 cols tile] = aT[256][R0S] @ W1[256][512]
// k-slabs of 16 rows (32KB) staged via register relay; thread tile 4x8
// (rows rt*4..+3, cols ct*4..+3 and 256+ct*4..+3).
// ---------------------------------------------------------------------------
template<typename T>
__device__ __forceinline__ void ffn_gemm1(T yacc[4][8], const float* __restrict__ W1,
                                          const float* r0, float* r1,
                                          int rt, int ct, int tid)
{
    #pragma unroll
    for (int i = 0; i < 4; i++)
        #pragma unroll
        for (int j = 0; j < 8; j++) yacc[i][j] = 0;
    float4 R[4];
    #pragma unroll
    for (int u = 0; u < 4; u++) R[u] = *(const float4*)(W1 + (tid + BT*u)*4);
    for (int k0 = 0; k0 < HID; k0 += 16) {
        #pragma unroll
        for (int u = 0; u < 4; u++) *(float4*)(r1 + (tid + BT*u)*4) = R[u];
        __syncthreads();
        if (k0 + 16 < HID) {
            const float* src = W1 + (long)(k0 + 16) * EXPD;
            #pragma unroll
            for (int u = 0; u < 4; u++) R[u] = *(const float4*)(src + (tid + BT*u)*4);
        }
        #pragma unroll 2
        for (int k = 0; k < 16; k++) {
            float4 av = *(const float4*)(r0 + (k0 + k)*R0S + rt*4);     // broadcast
            float4 w0 = *(const float4*)(r1 + k*EXPD + ct*4);           // contiguous
            float4 w1 = *(const float4*)(r1 + k*EXPD + 256 + ct*4);
            T a[4]  = {(T)av.x, (T)av.y, (T)av.z, (T)av.w};
            T wv[8] = {(T)w0.x, (T)w0.y, (T)w0.z, (T)w0.w,
                       (T)w1.x, (T)w1.y, (T)w1.z, (T)w1.w};
            #pragma unroll
            for (int i = 0; i < 4; i++)
                #pragma unroll
                for (int j = 0; j < 8; j++)
                    yacc[i][j] += a[i] * wv[j];
        }
        __syncthreads();
    }
}

// ---------------------------------------------------------------------------
// GEMM2-style accumulate: acc[4][4] += aT[E][R0S] @ W[E][256]
// e-slabs of 32 rows (32KB) staged via register relay; thread tile 4x4.
// Used for FFN-GEMM2 halves (E=256), enc entry (E=54), dec entry (E=32).
// ---------------------------------------------------------------------------
template<typename T>
__device__ __forceinline__ void gemm2_acc(T acc[4][4], const float* __restrict__ W, int E,
                                          const float* r0, float* r1,
                                          int rt, int ct, int tid)
{
    float4 R[4];
    {
        int n0 = (E < 32 ? E : 32) * 64;
        #pragma unroll
        for (int u = 0; u < 4; u++) {
            int idx = tid + BT*u;
            if (idx < n0) R[u] = *(const float4*)(W + idx*4);
        }
    }
    for (int e0 = 0; e0 < E; e0 += 32) {
        int n = E - e0; if (n > 32) n = 32;
        #pragma unroll
        for (int u = 0; u < 4; u++) {
            int idx = tid + BT*u;
            if (idx < n*64) *(float4*)(r1 + idx*4) = R[u];
        }
        __syncthreads();
        if (e0 + 32 < E) {
            int n2 = E - e0 - 32; if (n2 > 32) n2 = 32;
            const float* src = W + (long)(e0 + 32) * HID;
            #pragma unroll
            for (int u = 0; u < 4; u++) {
                int idx = tid + BT*u;
                if (idx < n2*64) R[u] = *(const float4*)(src + idx*4);
            }
        }
        #pragma unroll 2
        for (int e = 0; e < n; e++) {
            float4 av = *(const float4*)(r0 + (e0 + e)*R0S + rt*4);     // broadcast
            float4 wv = *(const float4*)(r1 + e*HID + ct*4);            // contiguous
            T a[4] = {(T)av.x, (T)av.y, (T)av.z, (T)av.w};
            T w[4] = {(T)wv.x, (T)wv.y, (T)wv.z, (T)wv.w};
            #pragma unroll
            for (int i = 0; i < 4; i++)
                #pragma unroll
                for (int j = 0; j < 4; j++)
                    acc[i][j] += a[i] * w[j];
        }
        __syncthreads();
    }
}

// ---------------------------------------------------------------------------
// One residual FFN block: acc = acc + gelu(LN(acc) @ W1 + b1) @ W2 + b2
// ---------------------------------------------------------------------------
template<typename T>
__device__ __forceinline__ void ffn_layer(T acc[4][4], float* r0, float* r1,
    const float* lng, const float* lnb,
    const float* W1, const float* b1, const float* W2, const float* b2,
    int rt, int ct, int tid)
{
    ln_to_abuf<T>(acc, r0, lng, lnb, b2, rt, ct);
    T yacc[4][8];
    ffn_gemm1<T>(yacc, W1, r0, r1, rt, ct, tid);   // ends with barrier
    #pragma unroll
    for (int h = 0; h < 2; h++) {
        float4 b1v = *(const float4*)(b1 + h*256 + ct*4);
        float bb[4] = {b1v.x, b1v.y, b1v.z, b1v.w};
        #pragma unroll
        for (int j = 0; j < 4; j++) {
            float4 o;
            o.x = (float)gelu_T<T>(yacc[0][h*4 + j] + (T)bb[j]);
            o.y = (float)gelu_T<T>(yacc[1][h*4 + j] + (T)bb[j]);
            o.z = (float)gelu_T<T>(yacc[2][h*4 + j] + (T)bb[j]);
            o.w = (float)gelu_T<T>(yacc[3][h*4 + j] + (T)bb[j]);
            *(float4*)(r0 + (ct*4 + j)*R0S + rt*4) = o;
        }
        gemm2_acc<T>(acc, W2 + (long)h*256*HID, 256, r0, r1, rt, ct, tid);
    }
}

// ---------------------------------------------------------------------------
// Encoder megakernel (f64 acc, f32 LDS storage) — cap 128 VGPR via (512,2)
// ---------------------------------------------------------------------------
__global__ __launch_bounds__(BT, 2)
void k_encoder(const float* __restrict__ x,
               const float* __restrict__ epw, const float* __restrict__ epb,
               const float* __restrict__ lng, const float* __restrict__ lnb,
               const float* __restrict__ W1, const float* __restrict__ b1,
               const float* __restrict__ W2, const float* __restrict__ b2,
               const float* __restrict__ ng, const float* __restrict__ nb,
               const float* __restrict__ Wl, const float* __restrict__ bl,
               const float* __restrict__ cb, float* __restrict__ dout)
{
    typedef double T;
    __shared__ __align__(16) char smem[78336];
    float*  r0   = (float*)smem;
    float*  r1   = (float*)(smem + 36864);
    double* zbuf = (double*)(smem + 69632);
    double* ccs  = (double*)(smem + 36864);     // overlays r1 (valid after Wl use)
    const int tid = threadIdx.x;
    const int rt = tid >> 6, ct = tid & 63;
    const long row0 = (long)blockIdx.x * ROWS;

    // stage xT [54][R0S]
    #pragma unroll
    for (int u = 0; u < 4; u++) {
        int idx = tid + BT*u;
        if (idx < ROWS * IN_DIM) {
            int r = idx / IN_DIM, c = idx % IN_DIM;
            r0[c*R0S + r] = x[row0*IN_DIM + idx];
        }
    }
    T acc[4][4];
    {
        float4 bv = *(const float4*)(epb + ct*4);
        float bb[4] = {bv.x, bv.y, bv.z, bv.w};
        #pragma unroll
        for (int i = 0; i < 4; i++)
            #pragma unroll
            for (int j = 0; j < 4; j++) acc[i][j] = (T)bb[j];
    }
    gemm2_acc<T>(acc, epw, IN_DIM, r0, r1, rt, ct, tid);

    for (int l = 0; l < NBLK; l++)
        ffn_layer<T>(acc, r0, r1, lng + l*HID, lnb + l*HID,
                     W1 + (long)l*HID*EXPD, b1 + l*EXPD,
                     W2 + (long)l*EXPD*HID, b2 + l*HID, rt, ct, tid);

    // final encoder LN
    ln_to_abuf<T>(acc, r0, ng, nb, nullptr, rt, ct);
    // stage Wl [256][32] into r1 (32KB)
    #pragma unroll
    for (int u = 0; u < 4; u++)
        *(float4*)(r1 + (tid + BT*u)*4) = *(const float4*)(Wl + (tid + BT*u)*4);
    __syncthreads();

    // latent projection, (r,q) map: r in 0..31, q in 0..15
    const int r = tid >> 4, q = tid & 15;
    {
        float2 blv = *(const float2*)(bl + q*2);
        T z0 = (T)blv.x, z1 = (T)blv.y;
        #pragma unroll 4
        for (int k = 0; k < HID; k++) {
            T a = (T)r0[k*R0S + r];                      // broadcast
            float2 w = *(const float2*)(r1 + k*LAT + q*2);
            z0 += a * (T)w.x; z1 += a * (T)w.y;
        }
        zbuf[r*34 + q*2] = z0; zbuf[r*34 + q*2 + 1] = z1;
    }
    __syncthreads();                                     // Wl dead; zbuf ready

    // codebook norms into ccs (overlaying r1): one code per thread
    {
        const float* cp = cb + (long)tid * LAT;
        T sc = 0;
        #pragma unroll
        for (int j = 0; j < LAT; j += 4) {
            float4 v = *(const float4*)(cp + j);
            sc += (T)v.x*(T)v.x + (T)v.y*(T)v.y + (T)v.z*(T)v.z + (T)v.w*(T)v.w;
        }
        ccs[tid] = sc;
    }
    __syncthreads();

    // VQ: thread (r,q) scans codes q*32..q*32+31
    T bd; int bi;
    {
        T zr[32];
        #pragma unroll
        for (int j = 0; j < LAT; j++) zr[j] = zbuf[r*34 + j];
        T zz = 0;
        #pragma unroll
        for (int j = 0; j < LAT; j++) zz += zr[j]*zr[j];
        bd = (T)1e300; bi = 0;
        for (int c0 = 0; c0 < 32; c0++) {
            int code = q*32 + c0;
            const float* cp = cb + (long)code * LAT;
            T dot = 0;
            #pragma unroll
            for (int j = 0; j < LAT; j += 4) {
                float4 v = *(const float4*)(cp + j);
                dot += zr[j]*(T)v.x + zr[j+1]*(T)v.y + zr[j+2]*(T)v.z + zr[j+3]*(T)v.w;
            }
            T d2 = (zz - 2.0*dot) + ccs[code];
            if (d2 < bd) { bd = d2; bi = code; }         // strict <: first-min
        }
        #pragma unroll
        for (int m = 1; m < 16; m <<= 1) {
            T ob = __shfl_xor(bd, m);
            int obi = __shfl_xor(bi, m);
            if (ob < bd || (ob == bd && obi < bi)) { bd = ob; bi = obi; }
        }
        if (q == 0) {
            long grow = row0 + r;
            dout[O_IDX + grow] = (float)bi;
            const float* cq = cb + (long)bi * LAT;
            #pragma unroll
            for (int j = 0; j < LAT; j += 4)
                *(float4*)(dout + O_ZQ + grow*LAT + j) = *(const float4*)(cq + j);
        }
    }
    // commit loss: wave sums -> block sum -> one atomic
    __syncthreads();                   // zbuf free for reuse
    T ws = bd;
    ws += __shfl_xor(ws, 16);
    ws += __shfl_xor(ws, 32);
    if ((tid & 63) == 0) zbuf[tid >> 6] = ws;
    __syncthreads();
    if (tid == 0) {
        T t = 0;
        #pragma unroll
        for (int w = 0; w < 8; w++) t += zbuf[w];
        atomicAdd(dout + O_LOSS, (float)t);
    }
}

// ---------------------------------------------------------------------------
// Decoder megakernel (f32) — round-1 proven (512,4): 32 waves/CU, f32 spill
// ---------------------------------------------------------------------------
__global__ __launch_bounds__(BT, 4)
void k_decoder(float* __restrict__ dout,
               const float* __restrict__ Wl, const float* __restrict__ bl,
               const float* __restrict__ lng, const float* __restrict__ lnb,
               const float* __restrict__ W1, const float* __restrict__ b1,
               const float* __restrict__ W2, const float* __restrict__ b2,
               const float* __restrict__ ng, const float* __restrict__ nb,
               const float* __restrict__ Wp, const float* __restrict__ pb)
{
    typedef float T;
    __shared__ __align__(16) char smem[69632];
    float* r0 = (float*)smem;
    float* r1 = (float*)(smem + 36864);
    const int tid = threadIdx.x;
    const int rt = tid >> 6, ct = tid & 63;
    const long row0 = (long)blockIdx.x * ROWS;

    // stage zqT [32][R0S]
    #pragma unroll
    for (int u = 0; u < 2; u++) {
        int idx = tid + BT*u;                  // < 1024
        int r = idx >> 5, c = idx & 31;
        r0[c*R0S + r] = dout[O_ZQ + row0*LAT + idx];
    }
    T acc[4][4];
    {
        float4 bv = *(const float4*)(bl + ct*4);
        float bb[4] = {bv.x, bv.y, bv.z, bv.w};
        #pragma unroll
        for (int i = 0; i < 4; i++)
            #pragma unroll
            for (int j = 0; j < 4; j++) acc[i][j] = bb[j];
    }
    gemm2_acc<T>(acc, Wl, LAT, r0, r1, rt, ct, tid);

    for (int l = 0; l < NBLK; l++)
        ffn_layer<T>(acc, r0, r1, lng + l*HID, lnb + l*HID,
                     W1 + (long)l*HID*EXPD, b1 + l*EXPD,
                     W2 + (long)l*EXPD*HID, b2 + l*HID, rt, ct, tid);

    ln_to_abuf<T>(acc, r0, ng, nb, nullptr, rt, ct);

    // output projection, (r,q) map; dpw staged in 2 k-chunks of 128
    const int r = tid >> 4, q = tid & 15;
    float oacc[4];
    #pragma unroll
    for (int j = 0; j < 4; j++) {
        int c = q*4 + j;
        oacc[j] = (c < IN_DIM) ? pb[c] : 0.f;
    }
    for (int k0 = 0; k0 < HID; k0 += 128) {
        #pragma unroll
        for (int u = 0; u < 4; u++) {
            int idx = tid + BT*u;
            if (idx < 1728)                   // 128*54/4 float4s
                ((float4*)r1)[idx] = ((const float4*)(Wp + (long)k0*IN_DIM))[idx];
        }
        __syncthreads();
        #pragma unroll 4
        for (int k = 0; k < 128; k++) {
            float a = r0[(k0 + k)*R0S + r];   // broadcast
            #pragma unroll
            for (int j = 0; j < 4; j++)
                oacc[j] += a * r1[k*IN_DIM + q*4 + j];   // may read pad garbage for c>=54
        }
        __syncthreads();
    }
    #pragma unroll
    for (int j = 0; j < 4; j++) {
        int c = q*4 + j;
        if (c < IN_DIM) dout[(row0 + r)*IN_DIM + c] = oacc[j];
    }
}

__global__ void k_zero(float* p) { *p = 0.0f; }
__global__ void k_final(float* p) { *p = *p * (1.0f / 8388608.0f); }  // / (B*LAT) = 2^-23, exact

// ---------------------------------------------------------------------------
extern "C" void kernel_launch(void* const* d_in, const int* in_sizes, int n_in,
                              void* d_out, int out_size, void* d_ws, size_t ws_size,
                              hipStream_t stream)
{
    (void)in_sizes; (void)n_in; (void)out_size; (void)d_ws; (void)ws_size;
    const float* x     = (const float*)d_in[0];
    const float* epw   = (const float*)d_in[1];
    const float* epb   = (const float*)d_in[2];
    const float* elng  = (const float*)d_in[3];
    const float* elnb  = (const float*)d_in[4];
    const float* ew1   = (const float*)d_in[5];
    const float* eb1   = (const float*)d_in[6];
    const float* ew2   = (const float*)d_in[7];
    const float* eb2   = (const float*)d_in[8];
    const float* eng   = (const float*)d_in[9];
    const float* enb   = (const float*)d_in[10];
    const float* elatw = (const float*)d_in[11];
    const float* elatb = (const float*)d_in[12];
    const float* cbk   = (const float*)d_in[13];
    const float* dlatw = (const float*)d_in[14];
    const float* dlatb = (const float*)d_in[15];
    const float* dlng  = (const float*)d_in[16];
    const float* dlnb  = (const float*)d_in[17];
    const float* dw1   = (const float*)d_in[18];
    const float* db1   = (const float*)d_in[19];
    const float* dw2   = (const float*)d_in[20];
    const float* db2   = (const float*)d_in[21];
    const float* dng   = (const float*)d_in[22];
    const float* dnb   = (const float*)d_in[23];
    const float* dpw   = (const float*)d_in[24];
    const float* dpb   = (const float*)d_in[25];
    float* out = (float*)d_out;

    dim3 blk(BT, 1, 1);
    k_zero<<<1, 1, 0, stream>>>(out + O_LOSS);
    k_encoder<<<BDIM / ROWS, blk, 0, stream>>>(
        x, epw, epb, elng, elnb, ew1, eb1, ew2, eb2, eng, enb, elatw, elatb, cbk, out);
    k_decoder<<<BDIM / ROWS, blk, 0, stream>>>(
        out, dlatw, dlatb, dlng, dlnb, dw1, db1, dw2, db2, dng, dnb, dpw, dpb);
    k_final<<<1, 1, 0, stream>>>(out + O_LOSS);
}

// Round 8
// 35689.941 us; speedup vs baseline: 1.2119x; 1.0368x over previous
//
#include <hip/hip_runtime.h>
#include <math.h>

#define BDIM   262144
#define IN_DIM 54
#define HID    256
#define EXPD   512
#define LAT    32
#define NBLK   4
#define NCODES 512
#define EPS    1e-5

#define BT     512     // threads per block
#define ROWS   32      // rows per block
#define R0S    36      // r0 column stride in floats (32 rows + 4 pad; float4-aligned)

// d_out layout (floats): x_recon | z_q_st | indices | commit_loss
#define O_ZQ   14155776
#define O_IDX  22544384
#define O_LOSS 22806528

// smem layout (bytes), both kernels 69632 total:
//   r0 [0,36864):        activations, transposed [c][R0S] f32 (rows 0..31 per col)
//   r1 [36864,69632):    weight slabs / Wl / dpw chunks (32KB)
//   enc only, overlaying r1 after Wl reads complete:
//     ccs  [36864,40960):  512 f64 codebook norms
//     zbuf [40960,49664):  32*34 f64 latents
//
// Occupancy model (measured r1-r7): __launch_bounds__ 2nd arg pins BOTH the
// VGPR budget and resident waves/EU ((512,4)->64VGPR/50%occ, (512,2)->
// 128cap/25%occ). To get 128-VGPR budget AND 16 waves/CU, use
// amdgpu_waves_per_eu(4) (budget 512/4=128, demand ~112 -> no spill) and let
// residency be resource-bound: 2 blocks x 8 waves = 16 waves/CU.

template<typename T> __device__ __forceinline__ T gelu_T(T x);
template<> __device__ __forceinline__ double gelu_T<double>(double x) {
    return 0.5 * x * (1.0 + erf(x * 0.70710678118654752440));
}
template<> __device__ __forceinline__ float gelu_T<float>(float x) {
    return 0.5f * x * (1.0f + erff(x * 0.70710678f));
}
template<typename T> __device__ __forceinline__ T rsqrt_T(T x);
template<> __device__ __forceinline__ double rsqrt_T<double>(double x) { return 1.0 / sqrt(x); }
template<> __device__ __forceinline__ float  rsqrt_T<float>(float x)  { return 1.0f / sqrtf(x); }

// ---------------------------------------------------------------------------
// LayerNorm: acc[4][4] regs (row rt*4+i, col ct*4+j) -> normalized f32 into
// r0 transposed [c][R0S]. Wave-local shfl reduction (each wave owns 4 rows).
// If b2 != null, preload residual bias into acc for the FFN accumulate.
// ---------------------------------------------------------------------------
template<typename T>
__device__ __forceinline__ void ln_to_abuf(T acc[4][4], float* r0,
    const float* __restrict__ g, const float* __restrict__ bta,
    const float* __restrict__ b2, int rt, int ct)
{
    T s[4], sq[4];
    #pragma unroll
    for (int i = 0; i < 4; i++) {
        s[i]  = acc[i][0] + acc[i][1] + acc[i][2] + acc[i][3];
        sq[i] = acc[i][0]*acc[i][0] + acc[i][1]*acc[i][1]
              + acc[i][2]*acc[i][2] + acc[i][3]*acc[i][3];
    }
    #pragma unroll
    for (int m = 1; m < 64; m <<= 1) {
        #pragma unroll
        for (int i = 0; i < 4; i++) {
            s[i]  += __shfl_xor(s[i],  m);
            sq[i] += __shfl_xor(sq[i], m);
        }
    }
    float4 gv = *(const float4*)(g + ct*4);
    float4 bv = *(const float4*)(bta + ct*4);
    float gj[4] = {gv.x, gv.y, gv.z, gv.w};
    float bj[4] = {bv.x, bv.y, bv.z, bv.w};
    T mu[4], rs[4];
    #pragma unroll
    for (int i = 0; i < 4; i++) {
        mu[i] = s[i] * (T)(1.0 / HID);
        T var = sq[i] * (T)(1.0 / HID) - mu[i] * mu[i];
        rs[i] = rsqrt_T<T>(var + (T)EPS);
    }
    #pragma unroll
    for (int j = 0; j < 4; j++) {
        float4 o;
        o.x = (float)((acc[0][j] - mu[0]) * rs[0] * (T)gj[j] + (T)bj[j]);
        o.y = (float)((acc[1][j] - mu[1]) * rs[1] * (T)gj[j] + (T)bj[j]);
        o.z = (float)((acc[2][j] - mu[2]) * rs[2] * (T)gj[j] + (T)bj[j]);
        o.w = (float)((acc[3][j] - mu[3]) * rs[3] * (T)gj[j] + (T)bj[j]);
        *(float4*)(r0 + (ct*4 + j)*R0S + rt*4) = o;
    }
    if (b2) {
        float4 b2v = *(const float4*)(b2 + ct*4);
        float bb[4] = {b2v.x, b2v.y, b2v.z, b2v.w};
        #pragma unroll
        for (int i = 0; i < 4; i++)
            #pragma unroll
            for (int j = 0; j < 4; j++)
                acc[i][j] += (T)bb[j];
    }
}

// ---------------------------------------------------------------------------
// GEMM1: yacc[32 rows x 512 cols tile] = aT[256][R0S] @ W1[256][512]
// k-slabs of 16 rows (32KB) staged via register relay; thread tile 4x8
// (rows rt*4..+3, cols ct*4..+3 and 256+ct*4..+3).
// ---------------------------------------------------------------------------
template<typename T>
__device__ __forceinline__ void ffn_gemm1(T yacc[4][8], const float* __restrict__ W1,
                                          const float* r0, float* r1,
                                          int rt, int ct, int tid)
{
    #pragma unroll
    for (int i = 0; i < 4; i++)
        #pragma unroll
        for (int j = 0; j < 8; j++) yacc[i][j] = 0;
    float4 R[4];
    #pragma unroll
    for (int u = 0; u < 4; u++) R[u] = *(const float4*)(W1 + (tid + BT*u)*4);
    for (int k0 = 0; k0 < HID; k0 += 16) {
        #pragma unroll
        for (int u = 0; u < 4; u++) *(float4*)(r1 + (tid + BT*u)*4) = R[u];
        __syncthreads();
        if (k0 + 16 < HID) {
            const float* src = W1 + (long)(k0 + 16) * EXPD;
            #pragma unroll
            for (int u = 0; u < 4; u++) R[u] = *(const float4*)(src + (tid + BT*u)*4);
        }
        #pragma unroll 2
        for (int k = 0; k < 16; k++) {
            float4 av = *(const float4*)(r0 + (k0 + k)*R0S + rt*4);     // broadcast
            float4 w0 = *(const float4*)(r1 + k*EXPD + ct*4);           // contiguous
            float4 w1 = *(const float4*)(r1 + k*EXPD + 256 + ct*4);
            T a[4]  = {(T)av.x, (T)av.y, (T)av.z, (T)av.w};
            T wv[8] = {(T)w0.x, (T)w0.y, (T)w0.z, (T)w0.w,
                       (T)w1.x, (T)w1.y, (T)w1.z, (T)w1.w};
            #pragma unroll
            for (int i = 0; i < 4; i++)
                #pragma unroll
                for (int j = 0; j < 8; j++)
                    yacc[i][j] += a[i] * wv[j];
        }
        __syncthreads();
    }
}

// ---------------------------------------------------------------------------
// GEMM2-style accumulate: acc[4][4] += aT[E][R0S] @ W[E][256]
// e-slabs of 32 rows (32KB) staged via register relay; thread tile 4x4.
// Used for FFN-GEMM2 halves (E=256), enc entry (E=54), dec entry (E=32).
// ---------------------------------------------------------------------------
template<typename T>
__device__ __forceinline__ void gemm2_acc(T acc[4][4], const float* __restrict__ W, int E,
                                          const float* r0, float* r1,
                                          int rt, int ct, int tid)
{
    float4 R[4];
    {
        int n0 = (E < 32 ? E : 32) * 64;
        #pragma unroll
        for (int u = 0; u < 4; u++) {
            int idx = tid + BT*u;
            if (idx < n0) R[u] = *(const float4*)(W + idx*4);
        }
    }
    for (int e0 = 0; e0 < E; e0 += 32) {
        int n = E - e0; if (n > 32) n = 32;
        #pragma unroll
        for (int u = 0; u < 4; u++) {
            int idx = tid + BT*u;
            if (idx < n*64) *(float4*)(r1 + idx*4) = R[u];
        }
        __syncthreads();
        if (e0 + 32 < E) {
            int n2 = E - e0 - 32; if (n2 > 32) n2 = 32;
            const float* src = W + (long)(e0 + 32) * HID;
            #pragma unroll
            for (int u = 0; u < 4; u++) {
                int idx = tid + BT*u;
                if (idx < n2*64) R[u] = *(const float4*)(src + idx*4);
            }
        }
        #pragma unroll 2
        for (int e = 0; e < n; e++) {
            float4 av = *(const float4*)(r0 + (e0 + e)*R0S + rt*4);     // broadcast
            float4 wv = *(const float4*)(r1 + e*HID + ct*4);            // contiguous
            T a[4] = {(T)av.x, (T)av.y, (T)av.z, (T)av.w};
            T w[4] = {(T)wv.x, (T)wv.y, (T)wv.z, (T)wv.w};
            #pragma unroll
            for (int i = 0; i < 4; i++)
                #pragma unroll
                for (int j = 0; j < 4; j++)
                    acc[i][j] += a[i] * w[j];
        }
        __syncthreads();
    }
}

// ---------------------------------------------------------------------------
// One residual FFN block: acc = acc + gelu(LN(acc) @ W1 + b1) @ W2 + b2
// ---------------------------------------------------------------------------
template<typename T>
__device__ __forceinline__ void ffn_layer(T acc[4][4], float* r0, float* r1,
    const float* lng, const float* lnb,
    const float* W1, const float* b1, const float* W2, const float* b2,
    int rt, int ct, int tid)
{
    ln_to_abuf<T>(acc, r0, lng, lnb, b2, rt, ct);
    T yacc[4][8];
    ffn_gemm1<T>(yacc, W1, r0, r1, rt, ct, tid);   // ends with barrier
    #pragma unroll
    for (int h = 0; h < 2; h++) {
        float4 b1v = *(const float4*)(b1 + h*256 + ct*4);
        float bb[4] = {b1v.x, b1v.y, b1v.z, b1v.w};
        #pragma unroll
        for (int j = 0; j < 4; j++) {
            float4 o;
            o.x = (float)gelu_T<T>(yacc[0][h*4 + j] + (T)bb[j]);
            o.y = (float)gelu_T<T>(yacc[1][h*4 + j] + (T)bb[j]);
            o.z = (float)gelu_T<T>(yacc[2][h*4 + j] + (T)bb[j]);
            o.w = (float)gelu_T<T>(yacc[3][h*4 + j] + (T)bb[j]);
            *(float4*)(r0 + (ct*4 + j)*R0S + rt*4) = o;
        }
        gemm2_acc<T>(acc, W2 + (long)h*256*HID, 256, r0, r1, rt, ct, tid);
    }
}

// ---------------------------------------------------------------------------
// Encoder megakernel (f64 acc, f32 LDS storage)
// ---------------------------------------------------------------------------
__global__ __launch_bounds__(BT) __attribute__((amdgpu_waves_per_eu(4)))
void k_encoder(const float* __restrict__ x,
               const float* __restrict__ epw, const float* __restrict__ epb,
               const float* __restrict__ lng, const float* __restrict__ lnb,
               const float* __restrict__ W1, const float* __restrict__ b1,
               const float* __restrict__ W2, const float* __restrict__ b2,
               const float* __restrict__ ng, const float* __restrict__ nb,
               const float* __restrict__ Wl, const float* __restrict__ bl,
               const float* __restrict__ cb, float* __restrict__ dout)
{
    typedef double T;
    __shared__ __align__(16) char smem[69632];
    float*  r0   = (float*)smem;
    float*  r1   = (float*)(smem + 36864);
    double* ccs  = (double*)(smem + 36864);     // overlays r1 (valid after Wl reads)
    double* zbuf = (double*)(smem + 40960);     // overlays r1+4KB
    const int tid = threadIdx.x;
    const int rt = tid >> 6, ct = tid & 63;
    const long row0 = (long)blockIdx.x * ROWS;

    // stage xT [54][R0S]
    #pragma unroll
    for (int u = 0; u < 4; u++) {
        int idx = tid + BT*u;
        if (idx < ROWS * IN_DIM) {
            int r = idx / IN_DIM, c = idx % IN_DIM;
            r0[c*R0S + r] = x[row0*IN_DIM + idx];
        }
    }
    T acc[4][4];
    {
        float4 bv = *(const float4*)(epb + ct*4);
        float bb[4] = {bv.x, bv.y, bv.z, bv.w};
        #pragma unroll
        for (int i = 0; i < 4; i++)
            #pragma unroll
            for (int j = 0; j < 4; j++) acc[i][j] = (T)bb[j];
    }
    gemm2_acc<T>(acc, epw, IN_DIM, r0, r1, rt, ct, tid);

    for (int l = 0; l < NBLK; l++)
        ffn_layer<T>(acc, r0, r1, lng + l*HID, lnb + l*HID,
                     W1 + (long)l*HID*EXPD, b1 + l*EXPD,
                     W2 + (long)l*EXPD*HID, b2 + l*HID, rt, ct, tid);

    // final encoder LN
    ln_to_abuf<T>(acc, r0, ng, nb, nullptr, rt, ct);
    // stage Wl [256][32] into r1 (32KB)
    #pragma unroll
    for (int u = 0; u < 4; u++)
        *(float4*)(r1 + (tid + BT*u)*4) = *(const float4*)(Wl + (tid + BT*u)*4);
    __syncthreads();

    // latent projection into REGISTERS (Wl still live in r1), (r,q) map
    const int r = tid >> 4, q = tid & 15;
    T z0, z1;
    {
        float2 blv = *(const float2*)(bl + q*2);
        z0 = (T)blv.x; z1 = (T)blv.y;
        #pragma unroll 4
        for (int k = 0; k < HID; k++) {
            T a = (T)r0[k*R0S + r];                      // broadcast
            float2 w = *(const float2*)(r1 + k*LAT + q*2);
            z0 += a * (T)w.x; z1 += a * (T)w.y;
        }
    }
    __syncthreads();                   // all Wl reads done; r1 reusable

    // store latents + codebook norms into the r1 overlay
    zbuf[r*34 + q*2] = z0; zbuf[r*34 + q*2 + 1] = z1;
    {
        const float* cp = cb + (long)tid * LAT;
        T sc = 0;
        #pragma unroll
        for (int j = 0; j < LAT; j += 4) {
            float4 v = *(const float4*)(cp + j);
            sc += (T)v.x*(T)v.x + (T)v.y*(T)v.y + (T)v.z*(T)v.z + (T)v.w*(T)v.w;
        }
        ccs[tid] = sc;
    }
    __syncthreads();

    // VQ: thread (r,q) scans codes q*32..q*32+31
    T bd; int bi;
    {
        T zr[32];
        #pragma unroll
        for (int j = 0; j < LAT; j++) zr[j] = zbuf[r*34 + j];
        T zz = 0;
        #pragma unroll
        for (int j = 0; j < LAT; j++) zz += zr[j]*zr[j];
        bd = (T)1e300; bi = 0;
        for (int c0 = 0; c0 < 32; c0++) {
            int code = q*32 + c0;
            const float* cp = cb + (long)code * LAT;
            T dot = 0;
            #pragma unroll
            for (int j = 0; j < LAT; j += 4) {
                float4 v = *(const float4*)(cp + j);
                dot += zr[j]*(T)v.x + zr[j+1]*(T)v.y + zr[j+2]*(T)v.z + zr[j+3]*(T)v.w;
            }
            T d2 = (zz - 2.0*dot) + ccs[code];
            if (d2 < bd) { bd = d2; bi = code; }         // strict <: first-min
        }
        #pragma unroll
        for (int m = 1; m < 16; m <<= 1) {
            T ob = __shfl_xor(bd, m);
            int obi = __shfl_xor(bi, m);
            if (ob < bd || (ob == bd && obi < bi)) { bd = ob; bi = obi; }
        }
        if (q == 0) {
            long grow = row0 + r;
            dout[O_IDX + grow] = (float)bi;
            const float* cq = cb + (long)bi * LAT;
            #pragma unroll
            for (int j = 0; j < LAT; j += 4)
                *(float4*)(dout + O_ZQ + grow*LAT + j) = *(const float4*)(cq + j);
        }
    }
    // commit loss: wave sums -> block sum -> one atomic
    __syncthreads();                   // zbuf reads done; free for reuse
    T ws = bd;
    ws += __shfl_xor(ws, 16);
    ws += __shfl_xor(ws, 32);
    if ((tid & 63) == 0) zbuf[tid >> 6] = ws;
    __syncthreads();
    if (tid == 0) {
        T t = 0;
        #pragma unroll
        for (int w = 0; w < 8; w++) t += zbuf[w];
        atomicAdd(dout + O_LOSS, (float)t);
    }
}

// ---------------------------------------------------------------------------
// Decoder megakernel (f32)
// ---------------------------------------------------------------------------
__global__ __launch_bounds__(BT) __attribute__((amdgpu_waves_per_eu(4)))
void k_decoder(float* __restrict__ dout,
               const float* __restrict__ Wl, const float* __restrict__ bl,
               const float* __restrict__ lng, const float* __restrict__ lnb,
               const float* __restrict__ W1, const float* __restrict__ b1,
               const float* __restrict__ W2, const float* __restrict__ b2,
               const float* __restrict__ ng, const float* __restrict__ nb,
               const float* __restrict__ Wp, const float* __restrict__ pb)
{
    typedef float T;
    __shared__ __align__(16) char smem[69632];
    float* r0 = (float*)smem;
    float* r1 = (float*)(smem + 36864);
    const int tid = threadIdx.x;
    const int rt = tid >> 6, ct = tid & 63;
    const long row0 = (long)blockIdx.x * ROWS;

    // stage zqT [32][R0S]
    #pragma unroll
    for (int u = 0; u < 2; u++) {
        int idx = tid + BT*u;                  // < 1024
        int r = idx >> 5, c = idx & 31;
        r0[c*R0S + r] = dout[O_ZQ + row0*LAT + idx];
    }
    T acc[4][4];
    {
        float4 bv = *(const float4*)(bl + ct*4);
        float bb[4] = {bv.x, bv.y, bv.z, bv.w};
        #pragma unroll
        for (int i = 0; i < 4; i++)
            #pragma unroll
            for (int j = 0; j < 4; j++) acc[i][j] = bb[j];
    }
    gemm2_acc<T>(acc, Wl, LAT, r0, r1, rt, ct, tid);

    for (int l = 0; l < NBLK; l++)
        ffn_layer<T>(acc, r0, r1, lng + l*HID, lnb + l*HID,
                     W1 + (long)l*HID*EXPD, b1 + l*EXPD,
                     W2 + (long)l*EXPD*HID, b2 + l*HID, rt, ct, tid);

    ln_to_abuf<T>(acc, r0, ng, nb, nullptr, rt, ct);

    // output projection, (r,q) map; dpw staged in 2 k-chunks of 128
    const int r = tid >> 4, q = tid & 15;
    float oacc[4];
    #pragma unroll
    for (int j = 0; j < 4; j++) {
        int c = q*4 + j;
        oacc[j] = (c < IN_DIM) ? pb[c] : 0.f;
    }
    for (int k0 = 0; k0 < HID; k0 += 128) {
        #pragma unroll
        for (int u = 0; u < 4; u++) {
            int idx = tid + BT*u;
            if (idx < 1728)                   // 128*54/4 float4s
                ((float4*)r1)[idx] = ((const float4*)(Wp + (long)k0*IN_DIM))[idx];
        }
        __syncthreads();
        #pragma unroll 4
        for (int k = 0; k < 128; k++) {
            float a = r0[(k0 + k)*R0S + r];   // broadcast
            #pragma unroll
            for (int j = 0; j < 4; j++)
                oacc[j] += a * r1[k*IN_DIM + q*4 + j];   // may read pad garbage for c>=54
        }
        __syncthreads();
    }
    #pragma unroll
    for (int j = 0; j < 4; j++) {
        int c = q*4 + j;
        if (c < IN_DIM) dout[(row0 + r)*IN_DIM + c] = oacc[j];
    }
}

__global__ void k_zero(float* p) { *p = 0.0f; }
__global__ void k_final(float* p) { *p = *p * (1.0f / 8388608.0f); }  // / (B*LAT) = 2^-23, exact

// ---------------------------------------------------------------------------
extern "C" void kernel_launch(void* const* d_in, const int* in_sizes, int n_in,
                              void* d_out, int out_size, void* d_ws, size_t ws_size,
                              hipStream_t stream)
{
    (void)in_sizes; (void)n_in; (void)out_size; (void)d_ws; (void)ws_size;
    const float* x     = (const float*)d_in[0];
    const float* epw   = (const float*)d_in[1];
    const float* epb   = (const float*)d_in[2];
    const float* elng  = (const float*)d_in[3];
    const float* elnb  = (const float*)d_in[4];
    const float* ew1   = (const float*)d_in[5];
    const float* eb1   = (const float*)d_in[6];
    const float* ew2   = (const float*)d_in[7];
    const float* eb2   = (const float*)d_in[8];
    const float* eng   = (const float*)d_in[9];
    const float* enb   = (const float*)d_in[10];
    const float* elatw = (const float*)d_in[11];
    const float* elatb = (const float*)d_in[12];
    const float* cbk   = (const float*)d_in[13];
    const float* dlatw = (const float*)d_in[14];
    const float* dlatb = (const float*)d_in[15];
    const float* dlng  = (const float*)d_in[16];
    const float* dlnb  = (const float*)d_in[17];
    const float* dw1   = (const float*)d_in[18];
    const float* db1   = (const float*)d_in[19];
    const float* dw2   = (const float*)d_in[20];
    const float* db2   = (const float*)d_in[21];
    const float* dng   = (const float*)d_in[22];
    const float* dnb   = (const float*)d_in[23];
    const float* dpw   = (const float*)d_in[24];
    const float* dpb   = (const float*)d_in[25];
    float* out = (float*)d_out;

    dim3 blk(BT, 1, 1);
    k_zero<<<1, 1, 0, stream>>>(out + O_LOSS);
    k_encoder<<<BDIM / ROWS, blk, 0, stream>>>(
        x, epw, epb, elng, elnb, ew1, eb1, ew2, eb2, eng, enb, elatw, elatb, cbk, out);
    k_decoder<<<BDIM / ROWS, blk, 0, stream>>>(
        out, dlatw, dlatb, dlng, dlnb, dw1, db1, dw2, db2, dng, dnb, dpw, dpb);
    k_final<<<1, 1, 0, stream>>>(out + O_LOSS);
}